// Round 4
// baseline (217.558 us; speedup 1.0000x reference)
//
#include <hip/hip_runtime.h>
#include <math.h>

#define LOOKBACK 336
#define NFEAT    164
#define HORIZON  96
#define DMODEL   64
#define DSTATE   16
#define DINNER   128
#define DTRANK   4
#define MLPH     64
#define BATCH    512
#define NSEG     4
#define SEG      84      // timesteps per segment (4*84 = 336)
#define TCK      28      // timesteps per chunk within a segment (3 chunks)
#define XCP      132     // padded row stride

// workspace layout (floats)
#define WS_H_ELEMS     (BATCH * NSEG * DINNER * DSTATE)   // 4,194,304
#define WS_DELTA_OFF   WS_H_ELEMS
#define WS_DELTA_ELEMS (BATCH * NSEG * DINNER)            // 262,144
#define WS_XCL_OFF     (WS_DELTA_OFF + WS_DELTA_ELEMS)
#define WS_XCL_ELEMS   (BATCH * DINNER)                   // 65,536

__device__ __forceinline__ float fast_rcp(float x) { return __builtin_amdgcn_rcpf(x); }
__device__ __forceinline__ float silu_f(float x) {
    return x * fast_rcp(1.f + __expf(-x));
}
__device__ __forceinline__ float softplus_f(float x) {
    return (x > 15.f) ? x : __logf(1.f + __expf(x));
}

// ================= kernel 1: per-segment conv + x_dbl + partial scan =========
__global__ __launch_bounds__(256, 5) void mamba_part(
    const float* __restrict__ x_raw,   // (512,336)
    const float* __restrict__ embed_W, const float* __restrict__ embed_b,
    const float* __restrict__ in_W,    // (64,256)
    const float* __restrict__ conv_W,  const float* __restrict__ conv_b,
    const float* __restrict__ xproj_W, // (128,36)
    const float* __restrict__ dt_W,    const float* __restrict__ dt_b,
    const float* __restrict__ A_log,
    float* __restrict__ ws_h, float* __restrict__ ws_delta,
    float* __restrict__ ws_xclast)
{
    __shared__ __align__(16) float xrl[88];           // segment + 3-halo
    __shared__ __align__(16) float w1x[DINNER], w0x[DINNER];
    __shared__ __align__(16) float xprojT[20][XCP];
    __shared__ __align__(16) float xc[TCK][XCP];
    __shared__ __align__(16) float Bsh[TCK][DSTATE];
    __shared__ __align__(16) float dtraw[TCK][DTRANK];

    const int tid = threadIdx.x;
    const int bid = blockIdx.x;
    const int b = bid >> 2, s = bid & 3;
    const int t0seg = s * SEG;

    // ---- prologue ----
    if (tid < 87) {
        int gt = t0seg - 3 + tid;
        xrl[tid] = (gt >= 0) ? x_raw[b*LOOKBACK + gt] : 0.f;
    }
    if (tid < DINNER) {   // rank-1 embed folded through in_W (x-half cols only)
        float a1 = 0.f, a0 = 0.f;
        for (int dm = 0; dm < DMODEL; ++dm) {
            float w = in_W[dm*(2*DINNER) + tid];
            a1 = fmaf(embed_W[dm], w, a1);
            a0 = fmaf(embed_b[dm], w, a0);
        }
        w1x[tid] = a1; w0x[tid] = a0;
    }
    for (int idx = tid; idx < 20*DINNER; idx += 256) {
        int jj = idx >> 7, d = idx & 127;
        xprojT[jj][d] = xproj_W[d*36 + jj];
    }
    __syncthreads();

    // conv-thread constants
    const int   dA1 = tid & 127;
    const int   par = tid >> 7;
    const float w1d = w1x[dA1], w0d = w0x[dA1];
    const float cw0 = conv_W[dA1*4+0], cw1 = conv_W[dA1*4+1],
                cw2 = conv_W[dA1*4+2], cw3 = conv_W[dA1*4+3];
    const float cb  = conv_b[dA1];

    // scan-thread constants: 2 threads/channel, 8 states each
    const int dB = tid >> 1;
    const int n0 = (tid & 1) * 8;
    const float dtw0 = dt_W[0*DINNER + dB], dtw1 = dt_W[1*DINNER + dB],
                dtw2 = dt_W[2*DINNER + dB], dtw3 = dt_W[3*DINNER + dB];
    const float dtb_r = dt_b[dB];
    float Areg[8], h[8];
    bool structured = true;
    #pragma unroll
    for (int i = 0; i < 8; ++i) {
        Areg[i] = -__expf(A_log[dB*DSTATE + n0 + i]);
        float expect = (float)(n0 + i + 1);
        structured = structured && (fabsf(Areg[i] + expect) < 1e-3f * expect);
        h[i] = 0.f;
    }
    float dacc = 0.f;   // sum of delta over this segment (per channel)

    // ---- 3 chunks of 28 ----
    for (int c = 0; c < 3; ++c) {
        const int cbase = c * TCK;
        const bool guard = (t0seg == 0) && (c == 0);

        // conv + silu for this chunk
        if (!guard) {
            #pragma unroll 4
            for (int ii = 0; ii < TCK/2; ++ii) {
                int tt = par + 2*ii;
                int tl = cbase + tt;           // local t; taps = xrl[tl..tl+3]
                float e0 = fmaf(xrl[tl  ], w1d, w0d);
                float e1 = fmaf(xrl[tl+1], w1d, w0d);
                float e2 = fmaf(xrl[tl+2], w1d, w0d);
                float e3 = fmaf(xrl[tl+3], w1d, w0d);
                float acc = cb + e0*cw0 + e1*cw1 + e2*cw2 + e3*cw3;
                float v = silu_f(acc);
                xc[tt][dA1] = v;
                if (t0seg + tl == LOOKBACK-1) ws_xclast[b*DINNER + dA1] = v;
            }
        } else {  // s==0, c==0: zero-padding means skipped taps, not embed(0)
            #pragma unroll 4
            for (int ii = 0; ii < TCK/2; ++ii) {
                int tt = par + 2*ii;
                int tl = tt;                   // gt == tl here
                float acc = cb;
                if (tl >= 3) acc = fmaf(fmaf(xrl[tl  ], w1d, w0d), cw0, acc);
                if (tl >= 2) acc = fmaf(fmaf(xrl[tl+1], w1d, w0d), cw1, acc);
                if (tl >= 1) acc = fmaf(fmaf(xrl[tl+2], w1d, w0d), cw2, acc);
                acc = fmaf(fmaf(xrl[tl+3], w1d, w0d), cw3, acc);
                xc[tt][dA1] = silu_f(acc);
            }
        }
        __syncthreads();

        // A2: [28 x 128] @ [128 x 20] -> dtraw(4) + Bsh(16)
        if (tid < 140) {
            const int r0 = tid / 10;
            const int j0 = (tid - r0*10) * 2;
            const float* p0 = &xprojT[j0][0];
            const float* p1 = &xprojT[j0+1][0];
            #pragma unroll
            for (int pass = 0; pass < 2; ++pass) {
                const int tt = r0 + 14*pass;
                float a0 = 0.f, a1 = 0.f;
                const float* xrow = &xc[tt][0];
                #pragma unroll 4
                for (int d = 0; d < DINNER; d += 4) {
                    float4 xv = *(const float4*)(xrow + d);
                    float4 q0 = *(const float4*)(p0 + d);
                    float4 q1 = *(const float4*)(p1 + d);
                    a0 += xv.x*q0.x + xv.y*q0.y + xv.z*q0.z + xv.w*q0.w;
                    a1 += xv.x*q1.x + xv.y*q1.y + xv.z*q1.z + xv.w*q1.w;
                }
                if (j0 < 4) { float2 r = {a0, a1}; *(float2*)&dtraw[tt][j0] = r; }
                else        { float2 r = {a0, a1}; *(float2*)&Bsh[tt][j0-4] = r; }
            }
        }
        __syncthreads();

        // scan this chunk
        if (structured) {
            #pragma unroll 4
            for (int tt = 0; tt < TCK; ++tt) {
                float4 dr = *(const float4*)&dtraw[tt][0];     // broadcast
                float dv = fmaf(dr.x, dtw0, fmaf(dr.y, dtw1,
                           fmaf(dr.z, dtw2, fmaf(dr.w, dtw3, dtb_r))));
                float e  = __expf(dv);
                float p  = 1.f + e;
                float r  = fast_rcp(p);                  // exp(-delta)
                float dl = (dv > 80.f) ? dv : __logf(p); // delta
                dacc += dl;
                float ux = dl * xc[tt][dB];
                float4 b0 = *(const float4*)&Bsh[tt][n0];
                float4 b1 = *(const float4*)&Bsh[tt][n0 + 4];
                float r2 = r*r,  r3 = r2*r, r4 = r2*r2;
                float t4 = r4*r, t5 = r4*r2, t6 = r4*r3, t7 = r4*r4;
                float q  = (n0 == 0) ? 1.f : t7;
                h[0] = fmaf(r *q, h[0], ux*b0.x);
                h[1] = fmaf(r2*q, h[1], ux*b0.y);
                h[2] = fmaf(r3*q, h[2], ux*b0.z);
                h[3] = fmaf(r4*q, h[3], ux*b0.w);
                h[4] = fmaf(t4*q, h[4], ux*b1.x);
                h[5] = fmaf(t5*q, h[5], ux*b1.y);
                h[6] = fmaf(t6*q, h[6], ux*b1.z);
                h[7] = fmaf(t7*q, h[7], ux*b1.w);
            }
        } else {
            #pragma unroll 2
            for (int tt = 0; tt < TCK; ++tt) {
                float4 dr = *(const float4*)&dtraw[tt][0];
                float dv = fmaf(dr.x, dtw0, fmaf(dr.y, dtw1,
                           fmaf(dr.z, dtw2, fmaf(dr.w, dtw3, dtb_r))));
                float dl = softplus_f(dv);
                dacc += dl;
                float ux = dl * xc[tt][dB];
                float4 b0 = *(const float4*)&Bsh[tt][n0];
                float4 b1 = *(const float4*)&Bsh[tt][n0 + 4];
                h[0] = fmaf(__expf(dl*Areg[0]), h[0], ux*b0.x);
                h[1] = fmaf(__expf(dl*Areg[1]), h[1], ux*b0.y);
                h[2] = fmaf(__expf(dl*Areg[2]), h[2], ux*b0.z);
                h[3] = fmaf(__expf(dl*Areg[3]), h[3], ux*b0.w);
                h[4] = fmaf(__expf(dl*Areg[4]), h[4], ux*b1.x);
                h[5] = fmaf(__expf(dl*Areg[5]), h[5], ux*b1.y);
                h[6] = fmaf(__expf(dl*Areg[6]), h[6], ux*b1.z);
                h[7] = fmaf(__expf(dl*Areg[7]), h[7], ux*b1.w);
            }
        }
        __syncthreads();   // protect xc/dtraw/Bsh before next chunk's writes
    }

    // ---- write partials (coalesced: 16B/lane, consecutive) ----
    {
        float4 v0 = {h[0], h[1], h[2], h[3]};
        float4 v1 = {h[4], h[5], h[6], h[7]};
        float4* hp = (float4*)&ws_h[bid*(DINNER*DSTATE) + dB*DSTATE + n0];
        hp[0] = v0; hp[1] = v1;
    }
    if (n0 == 0) ws_delta[bid*DINNER + dB] = dacc;
}

// ================= kernel 2: combine segments + epilogue + MLP + head ========
__global__ __launch_bounds__(256, 2) void mamba_combine(
    const float* __restrict__ x_raw, const float* __restrict__ x_features,
    const float* __restrict__ embed_W, const float* __restrict__ embed_b,
    const float* __restrict__ in_W, const float* __restrict__ xproj_W,
    const float* __restrict__ A_log, const float* __restrict__ Dvec,
    const float* __restrict__ out_W,
    const float* __restrict__ mlp_W1, const float* __restrict__ mlp_b1,
    const float* __restrict__ mlp_W2, const float* __restrict__ mlp_b2,
    const float* __restrict__ head_W, const float* __restrict__ head_b,
    const float* __restrict__ ws_h, const float* __restrict__ ws_delta,
    const float* __restrict__ ws_xclast,
    float* __restrict__ out)
{
    __shared__ float xcl[DINNER], zs[DINNER], Cl[DSTATE], yv[DINNER];
    __shared__ float hfin[96], mlph[MLPH];

    const int tid = threadIdx.x;
    const int b   = blockIdx.x;
    const int dB  = tid >> 1;
    const int n0  = (tid & 1) * 8;

    // combine partial h:  h = sum_s exp(A * S_s) * h_s,  S_s = suffix delta sum
    float Areg[8];
    #pragma unroll
    for (int i = 0; i < 8; ++i) Areg[i] = -__expf(A_log[dB*DSTATE + n0 + i]);
    float d1 = ws_delta[(b*4+1)*DINNER + dB];
    float d2 = ws_delta[(b*4+2)*DINNER + dB];
    float d3 = ws_delta[(b*4+3)*DINNER + dB];
    float Ss[3] = {d1+d2+d3, d2+d3, d3};
    float hc[8];
    {   const float4* hp = (const float4*)&ws_h[(b*4+3)*(DINNER*DSTATE) + dB*DSTATE + n0];
        float4 a = hp[0], c = hp[1];
        hc[0]=a.x; hc[1]=a.y; hc[2]=a.z; hc[3]=a.w;
        hc[4]=c.x; hc[5]=c.y; hc[6]=c.z; hc[7]=c.w;
    }
    #pragma unroll
    for (int s = 0; s < 3; ++s) {
        const float4* hp = (const float4*)&ws_h[(b*4+s)*(DINNER*DSTATE) + dB*DSTATE + n0];
        float4 a = hp[0], c = hp[1];
        float hs[8] = {a.x,a.y,a.z,a.w,c.x,c.y,c.z,c.w};
        float S = Ss[s];
        #pragma unroll
        for (int i = 0; i < 8; ++i) hc[i] = fmaf(__expf(Areg[i]*S), hs[i], hc[i]);
    }

    // phase 1: xc_last, z-gate, MLP stage 1
    if (tid < DINNER) {
        xcl[tid] = ws_xclast[b*DINNER + tid];
        float a1 = 0.f, a0 = 0.f;
        for (int dm = 0; dm < DMODEL; ++dm) {
            float w = in_W[dm*(2*DINNER) + DINNER + tid];   // z-half cols
            a1 = fmaf(embed_W[dm], w, a1);
            a0 = fmaf(embed_b[dm], w, a0);
        }
        float zv = fmaf(x_raw[b*LOOKBACK + LOOKBACK-1], a1, a0);
        zs[tid] = silu_f(zv);
    } else if (tid < 192) {
        int j = tid - 128;
        float acc = mlp_b1[j];
        const float* xf = x_features + b*NFEAT;
        for (int f = 0; f < NFEAT; ++f) acc = fmaf(xf[f], mlp_W1[f*MLPH + j], acc);
        mlph[j] = fmaxf(acc, 0.f);
    }
    __syncthreads();

    // phase 2: C at t=335, MLP stage 2
    if (tid < DSTATE) {
        float acc = 0.f;
        for (int d = 0; d < DINNER; ++d) acc = fmaf(xcl[d], xproj_W[d*36 + 20 + tid], acc);
        Cl[tid] = acc;
    } else if (tid >= 32 && tid < 64) {
        int j = tid - 32;
        float acc = mlp_b2[j];
        for (int k = 0; k < MLPH; ++k) acc = fmaf(mlph[k], mlp_W2[k*32 + j], acc);
        hfin[64 + j] = acc;
    }
    __syncthreads();

    // phase 3: y = (h·C + xc_last*D) * silu(z)
    {
        float part = 0.f;
        #pragma unroll
        for (int i = 0; i < 8; ++i) part = fmaf(hc[i], Cl[n0 + i], part);
        float other = __shfl_xor(part, 1);
        if ((tid & 1) == 0) {
            float y = part + other + xcl[dB]*Dvec[dB];
            yv[dB] = y * zs[dB];
        }
    }
    __syncthreads();

    // phase 4: out projection
    if (tid < DMODEL) {
        float acc = 0.f;
        for (int d = 0; d < DINNER; ++d) acc = fmaf(yv[d], out_W[d*DMODEL + tid], acc);
        hfin[tid] = acc;
    }
    __syncthreads();

    // phase 5: head
    if (tid < HORIZON) {
        float acc = head_b[tid];
        for (int i = 0; i < 96; ++i) acc = fmaf(hfin[i], head_W[i*HORIZON + tid], acc);
        out[b*HORIZON + tid] = acc;
    }
}

extern "C" void kernel_launch(void* const* d_in, const int* in_sizes, int n_in,
                              void* d_out, int out_size, void* d_ws, size_t ws_size,
                              hipStream_t stream) {
    (void)in_sizes; (void)n_in; (void)out_size; (void)ws_size;
    float* ws        = (float*)d_ws;
    float* ws_h      = ws;
    float* ws_delta  = ws + WS_DELTA_OFF;
    float* ws_xclast = ws + WS_XCL_OFF;

    mamba_part<<<BATCH*NSEG, 256, 0, stream>>>(
        (const float*)d_in[0],  (const float*)d_in[2],  (const float*)d_in[3],
        (const float*)d_in[4],  (const float*)d_in[5],  (const float*)d_in[6],
        (const float*)d_in[7],  (const float*)d_in[8],  (const float*)d_in[9],
        (const float*)d_in[10],
        ws_h, ws_delta, ws_xclast);

    mamba_combine<<<BATCH, 256, 0, stream>>>(
        (const float*)d_in[0],  (const float*)d_in[1],  (const float*)d_in[2],
        (const float*)d_in[3],  (const float*)d_in[4],  (const float*)d_in[7],
        (const float*)d_in[10], (const float*)d_in[11], (const float*)d_in[12],
        (const float*)d_in[13], (const float*)d_in[14], (const float*)d_in[15],
        (const float*)d_in[16], (const float*)d_in[17], (const float*)d_in[18],
        ws_h, ws_delta, ws_xclast,
        (float*)d_out);
}